// Round 1
// baseline (116.400 us; speedup 1.0000x reference)
//
#include <hip/hip_runtime.h>

#define NB 512      // atoms per batch
#define BB 4        // batch
#define FD 64       // feature dim
#define NRBF 25
#define KTAB 448    // interpolation table rows
#define ITILE 16
#define JCHUNK 128

__device__ __forceinline__ float ssp(float x) {
    // softplus(x) - ln2, numerically stable
    return fmaxf(x, 0.0f) + log1pf(expf(-fabsf(x))) - 0.69314718055994531f;
}

// k_pre: workgroups 0..127: per-row work (post-MLP of previous block + residual,
//        then f = x @ in2f[t]). workgroups 128..239: build interp table T_ws for block t.
__global__ __launch_bounds__(256) void schnet_pre(
    int t,
    const float* __restrict__ emb,
    float* __restrict__ x_buf,
    const float* __restrict__ y_ws,
    const float* __restrict__ in2f,
    const float* __restrict__ fw1, const float* __restrict__ fb1,
    const float* __restrict__ fw2, const float* __restrict__ fb2,
    const float* __restrict__ f2o, const float* __restrict__ f2b,
    const float* __restrict__ dw,  const float* __restrict__ db,
    float* __restrict__ f_ws, float* __restrict__ T_ws)
{
    int wg = blockIdx.x;
    int tid = threadIdx.x;
    if (wg < 128) {
        __shared__ float wA[FD*FD];   // f2o[t-1]
        __shared__ float wB[FD*FD];   // dw[t-1]
        __shared__ float wC[FD*FD];   // in2f[t]
        __shared__ float bA[FD], bB[FD];
        __shared__ float r1[4][FD], r2[4][FD];
        for (int s = tid; s < FD*FD; s += 256) wC[s] = in2f[t*FD*FD + s];
        if (t > 0) {
            for (int s = tid; s < FD*FD; s += 256) wA[s] = f2o[(t-1)*FD*FD + s];
            for (int s = tid; s < FD*FD; s += 256) wB[s] = dw[(t-1)*FD*FD + s];
            if (tid < FD) { bA[tid] = f2b[(t-1)*FD + tid]; bB[tid] = db[(t-1)*FD + tid]; }
        }
        __syncthreads();
        int wave = tid >> 6, lane = tid & 63;
        for (int rr = 0; rr < 4; ++rr) {
            int row = wg*16 + wave*4 + rr;   // 0..2047
            float xn;
            if (t == 0) {
                xn = emb[(size_t)row*FD + lane];
            } else {
                float y = 0.0f;
                for (int c = 0; c < 8; ++c)
                    y += y_ws[((size_t)c*2048 + row)*FD + lane];
                r1[wave][lane] = y;
                __syncthreads();
                float z = bA[lane];
                for (int f = 0; f < FD; ++f) z += r1[wave][f] * wA[f*FD + lane];
                float u = ssp(z);
                r2[wave][lane] = u;
                __syncthreads();
                float y3 = bB[lane];
                for (int g = 0; g < FD; ++g) y3 += r2[wave][g] * wB[g*FD + lane];
                const float* xin = (t == 1) ? emb : x_buf;
                xn = xin[(size_t)row*FD + lane] + y3;
                x_buf[(size_t)row*FD + lane] = xn;
                __syncthreads();
            }
            r1[wave][lane] = xn;
            __syncthreads();
            float fo = 0.0f;
            for (int f = 0; f < FD; ++f) fo += r1[wave][f] * wC[f*FD + lane];
            f_ws[(size_t)row*FD + lane] = fo;
            __syncthreads();
        }
    } else {
        // table build: 112 wgs x 4 rows each
        __shared__ float ub[4][FD];
        int kr = tid >> 6, g = tid & 63;
        int k = (wg - 128)*4 + kr;
        float dk = (float)k * (5.0f/447.0f);
        float h1 = fb1[t*FD + g];
        for (int r = 0; r < NRBF; ++r) {
            float s = dk - (float)r * (5.0f/24.0f);
            h1 += expf(-10.0f*s*s) * fw1[(t*NRBF + r)*FD + g];
        }
        ub[kr][g] = ssp(h1);
        __syncthreads();
        float T = fb2[t*FD + g];
        for (int gg = 0; gg < FD; ++gg) T += ub[kr][gg] * fw2[(t*FD + gg)*FD + g];
        T_ws[(size_t)k*FD + g] = T;
    }
}

// k_conv: y_partial[c8][b][i][f] = sum over a 64-j slice of f_j[f] * lerp(T, d_ij)[f]
__global__ __launch_bounds__(512) void schnet_conv(
    const float* __restrict__ dists,
    const float* __restrict__ f_ws,
    const float* __restrict__ T_ws,
    float* __restrict__ y_ws)
{
    __shared__ float T_lds[KTAB*FD];            // 114688 B
    __shared__ float f_lds[JCHUNK*FD];          // 32768 B
    __shared__ float d_lds[ITILE*(JCHUNK+4)];   // 8448 B (pad kills bank conflicts)
    int wgid = blockIdx.x;
    int jc = wgid & 3, it = (wgid >> 2) & 31, b = wgid >> 7;
    int tid = threadIdx.x;
    for (int s = tid; s < KTAB*FD/4; s += 512)
        ((float4*)T_lds)[s] = ((const float4*)T_ws)[s];
    const float* fsrc = f_ws + ((size_t)b*NB + jc*JCHUNK)*FD;
    for (int s = tid; s < JCHUNK*FD/4; s += 512)
        ((float4*)f_lds)[s] = ((const float4*)fsrc)[s];
    int i0 = it*ITILE;
    {
        int s = tid;                              // 512 elems total: one pass
        if (s < ITILE*JCHUNK/4) {
            int r = s / (JCHUNK/4), c = s % (JCHUNK/4);
            ((float4*)(d_lds + r*(JCHUNK+4)))[c] =
                ((const float4*)(dists + ((size_t)b*NB + i0 + r)*NB + jc*JCHUNK))[c];
        }
    }
    __syncthreads();
    int wave = tid >> 6, lane = tid & 63;
    int q = wave & 3, h = wave >> 2;
    int g = lane >> 4, fq = lane & 15;
    int il = q*4 + g;
    int jb = h*64;
    const float scale = 447.0f/5.0f;
    float ax = 0.f, ay = 0.f, az = 0.f, aw = 0.f;
    const float* drow = d_lds + il*(JCHUNK+4) + jb;
    const float* Tb = T_lds + fq*4;
    const float* fbp = f_lds + fq*4;
    for (int j4 = 0; j4 < 16; ++j4) {
        float4 dv = *(const float4*)(drow + j4*4);
        float dd[4] = {dv.x, dv.y, dv.z, dv.w};
        #pragma unroll
        for (int u = 0; u < 4; ++u) {
            float tt = fminf(fmaxf(dd[u], 0.0f)*scale, 446.999f);
            int k = (int)tt;
            float a = tt - (float)k;
            const float4 T0 = *(const float4*)(Tb + k*FD);
            const float4 T1 = *(const float4*)(Tb + (k+1)*FD);
            int jl = jb + j4*4 + u;
            const float4 fj = *(const float4*)(fbp + jl*FD);
            ax += fj.x * (T0.x + a*(T1.x - T0.x));
            ay += fj.y * (T0.y + a*(T1.y - T0.y));
            az += fj.z * (T0.z + a*(T1.z - T0.z));
            aw += fj.w * (T0.w + a*(T1.w - T0.w));
        }
    }
    int c8 = jc*2 + h;
    float* yp = y_ws + ((size_t)c8*2048 + (size_t)b*NB + i0 + il)*FD + fq*4;
    float4 acc; acc.x = ax; acc.y = ay; acc.z = az; acc.w = aw;
    *(float4*)yp = acc;
}

// k_final: last post-MLP + residual + readout MLP
__global__ __launch_bounds__(256) void schnet_final(
    const float* __restrict__ x_in,
    const float* __restrict__ y_ws,
    const float* __restrict__ f2o, const float* __restrict__ f2b,
    const float* __restrict__ dw,  const float* __restrict__ db,
    const float* __restrict__ aw1, const float* __restrict__ ab1,
    const float* __restrict__ aw2, const float* __restrict__ ab2,
    float* __restrict__ out)
{
    __shared__ float wA[FD*FD], wB[FD*FD];
    __shared__ float wA1[FD*32];
    __shared__ float bA[FD], bB[FD], b1s[32], w2s[32];
    __shared__ float r1[4][FD], r2[4][FD];
    int tid = threadIdx.x, wg = blockIdx.x;
    for (int s = tid; s < FD*FD; s += 256) { wA[s] = f2o[2*FD*FD + s]; wB[s] = dw[2*FD*FD + s]; }
    for (int s = tid; s < FD*32; s += 256) wA1[s] = aw1[s];
    if (tid < FD) { bA[tid] = f2b[2*FD + tid]; bB[tid] = db[2*FD + tid]; }
    if (tid < 32) { b1s[tid] = ab1[tid]; w2s[tid] = aw2[tid]; }
    __syncthreads();
    int wave = tid >> 6, lane = tid & 63;
    float ab2v = ab2[0];
    for (int rr = 0; rr < 4; ++rr) {
        int row = wg*16 + wave*4 + rr;
        float y = 0.0f;
        for (int c = 0; c < 8; ++c) y += y_ws[((size_t)c*2048 + row)*FD + lane];
        r1[wave][lane] = y;
        __syncthreads();
        float z = bA[lane];
        for (int f = 0; f < FD; ++f) z += r1[wave][f] * wA[f*FD + lane];
        float u = ssp(z);
        r2[wave][lane] = u;
        __syncthreads();
        float y3 = bB[lane];
        for (int gg = 0; gg < FD; ++gg) y3 += r2[wave][gg] * wB[gg*FD + lane];
        float x3 = x_in[(size_t)row*FD + lane] + y3;
        r1[wave][lane] = x3;
        float s1 = b1s[lane & 31];
        for (int f = 0; f < FD; ++f) s1 += r1[wave][f] * wA1[f*32 + (lane & 31)];
        float hh = ssp(s1) * w2s[lane & 31];
        r2[wave][lane] = hh;
        __syncthreads();
        if (lane == 0) {
            float sum = ab2v;
            for (int m = 0; m < 32; ++m) sum += r2[wave][m];
            out[row] = sum;
        }
        __syncthreads();
    }
}

extern "C" void kernel_launch(void* const* d_in, const int* in_sizes, int n_in,
                              void* d_out, int out_size, void* d_ws, size_t ws_size,
                              hipStream_t stream) {
    const float* emb  = (const float*)d_in[0];
    const float* dist = (const float*)d_in[1];
    const float* in2f = (const float*)d_in[2];
    const float* fw1  = (const float*)d_in[3];
    const float* fb1  = (const float*)d_in[4];
    const float* fw2  = (const float*)d_in[5];
    const float* fb2  = (const float*)d_in[6];
    const float* f2o  = (const float*)d_in[7];
    const float* f2b  = (const float*)d_in[8];
    const float* dwp  = (const float*)d_in[9];
    const float* dbp  = (const float*)d_in[10];
    const float* aw1  = (const float*)d_in[11];
    const float* ab1  = (const float*)d_in[12];
    const float* aw2  = (const float*)d_in[13];
    const float* ab2  = (const float*)d_in[14];
    float* out = (float*)d_out;
    float* ws = (float*)d_ws;
    float* T_ws  = ws;                       // 448*64        = 28672 floats
    float* f_ws  = ws + 28672;               // 4*512*64      = 131072
    float* x_buf = ws + 28672 + 131072;      // 131072
    float* y_ws  = ws + 28672 + 2*131072;    // 8*4*512*64    = 1048576
    for (int t = 0; t < 3; ++t) {
        hipLaunchKernelGGL(schnet_pre, dim3(240), dim3(256), 0, stream,
            t, emb, x_buf, y_ws, in2f, fw1, fb1, fw2, fb2, f2o, f2b, dwp, dbp, f_ws, T_ws);
        hipLaunchKernelGGL(schnet_conv, dim3(512), dim3(512), 0, stream,
            dist, f_ws, T_ws, y_ws);
    }
    hipLaunchKernelGGL(schnet_final, dim3(128), dim3(256), 0, stream,
        x_buf, y_ws, f2o, f2b, dwp, dbp, aw1, ab1, aw2, ab2, out);
}

// Round 2
// 108.582 us; speedup vs baseline: 1.0720x; 1.0720x over previous
//
#include <hip/hip_runtime.h>

#define NB 512      // atoms per batch
#define FD 64       // feature dim
#define NRBF 25
#define KTAB 448    // interpolation table rows
#define ITILE 32
#define JCHUNK 128
#define DPAD 132    // padded d-tile stride (il*132 mod 32 = il*4 -> conflict-free)

typedef _Float16 half2v __attribute__((ext_vector_type(2)));

__device__ __forceinline__ float ssp(float x) {
    // softplus(x) - ln2, numerically stable
    return fmaxf(x, 0.0f) + log1pf(expf(-fabsf(x))) - 0.69314718055994531f;
}

// k_pre: wgs 0..127: post-MLP of previous block + residual + f = x@in2f (f16 out).
//        wgs 128..239: build f32 interp table T_ws for block t.
__global__ __launch_bounds__(256) void schnet_pre(
    int t,
    const float* __restrict__ emb,
    float* __restrict__ x_buf,
    const float* __restrict__ y_ws,
    const float* __restrict__ in2f,
    const float* __restrict__ fw1, const float* __restrict__ fb1,
    const float* __restrict__ fw2, const float* __restrict__ fb2,
    const float* __restrict__ f2o, const float* __restrict__ f2b,
    const float* __restrict__ dw,  const float* __restrict__ db,
    unsigned short* __restrict__ f16w, float* __restrict__ T_ws)
{
    int wg = blockIdx.x;
    int tid = threadIdx.x;
    if (wg < 128) {
        __shared__ float wA[FD*FD];   // f2o[t-1]
        __shared__ float wB[FD*FD];   // dw[t-1]
        __shared__ float wC[FD*FD];   // in2f[t]
        __shared__ float bA[FD], bB[FD];
        __shared__ float r1[4][FD], r2[4][FD];
        for (int s = tid; s < FD*FD; s += 256) wC[s] = in2f[t*FD*FD + s];
        if (t > 0) {
            for (int s = tid; s < FD*FD; s += 256) wA[s] = f2o[(t-1)*FD*FD + s];
            for (int s = tid; s < FD*FD; s += 256) wB[s] = dw[(t-1)*FD*FD + s];
            if (tid < FD) { bA[tid] = f2b[(t-1)*FD + tid]; bB[tid] = db[(t-1)*FD + tid]; }
        }
        __syncthreads();
        int wave = tid >> 6, lane = tid & 63;
        for (int rr = 0; rr < 4; ++rr) {
            int row = wg*16 + wave*4 + rr;   // 0..2047
            float xn;
            if (t == 0) {
                xn = emb[(size_t)row*FD + lane];
            } else {
                float y = 0.0f;
                for (int c = 0; c < 4; ++c)
                    y += y_ws[((size_t)c*2048 + row)*FD + lane];
                r1[wave][lane] = y;
                __syncthreads();
                float z = bA[lane];
                for (int f = 0; f < FD; ++f) z += r1[wave][f] * wA[f*FD + lane];
                float u = ssp(z);
                r2[wave][lane] = u;
                __syncthreads();
                float y3 = bB[lane];
                for (int g = 0; g < FD; ++g) y3 += r2[wave][g] * wB[g*FD + lane];
                const float* xin = (t == 1) ? emb : x_buf;
                xn = xin[(size_t)row*FD + lane] + y3;
                x_buf[(size_t)row*FD + lane] = xn;
                __syncthreads();
            }
            r1[wave][lane] = xn;
            __syncthreads();
            float fo = 0.0f;
            for (int f = 0; f < FD; ++f) fo += r1[wave][f] * wC[f*FD + lane];
            union { _Float16 h; unsigned short u; } cv;
            cv.h = (_Float16)fo;
            f16w[(size_t)row*FD + lane] = cv.u;
            __syncthreads();
        }
    } else {
        // table build: 112 wgs x 4 rows each
        __shared__ float ub[4][FD];
        int kr = tid >> 6, g = tid & 63;
        int k = (wg - 128)*4 + kr;
        float dk = (float)k * (5.0f/447.0f);
        float h1 = fb1[t*FD + g];
        for (int r = 0; r < NRBF; ++r) {
            float s = dk - (float)r * (5.0f/24.0f);
            h1 += expf(-10.0f*s*s) * fw1[(t*NRBF + r)*FD + g];
        }
        ub[kr][g] = ssp(h1);
        __syncthreads();
        float T = fb2[t*FD + g];
        for (int gg = 0; gg < FD; ++gg) T += ub[kr][gg] * fw2[(t*FD + gg)*FD + g];
        T_ws[(size_t)k*FD + g] = T;
    }
}

// k_conv: y_partial[jc][b*512+i][f] = sum over this wg's 128-j slice of f_j[f]*lerp(T,d_ij)[f]
// LDS: paired f16 table (T_k | dT_k per 4-feature group), f16 f-chunk, padded d tile.
__global__ __launch_bounds__(512, 2) void schnet_conv(
    const float* __restrict__ dists,
    const unsigned short* __restrict__ f16w,
    const float* __restrict__ T_ws,
    float* __restrict__ y_ws)
{
    __shared__ unsigned int Tp[KTAB*16*4];      // 448*16 entries * 16 B = 114688 B
    __shared__ unsigned int f_l[JCHUNK*FD/2];   // 128*64 f16 = 16384 B
    __shared__ float d_l[ITILE*DPAD];           // 32*132*4 = 16896 B
    int wg = blockIdx.x;                        // 256 wgs: 4 jc x 16 it x 4 b
    int jc = wg & 3, it = (wg >> 2) & 15, b = wg >> 6;
    int tid = threadIdx.x;
    // pack f32 table -> paired f16 [T(4) | dT(4)] per (k, fq) entry
    for (int e = tid; e < KTAB*16; e += 512) {
        int k = e >> 4, fq = e & 15;
        const float4 A = *(const float4*)&T_ws[k*FD + fq*4];
        int k1 = (k < KTAB-1) ? (k+1) : k;
        const float4 Bv = *(const float4*)&T_ws[k1*FD + fq*4];
        half2v t01 = { (_Float16)A.x, (_Float16)A.y };
        half2v t23 = { (_Float16)A.z, (_Float16)A.w };
        half2v d01 = { (_Float16)(Bv.x - A.x), (_Float16)(Bv.y - A.y) };
        half2v d23 = { (_Float16)(Bv.z - A.z), (_Float16)(Bv.w - A.w) };
        uint4 o;
        o.x = __builtin_bit_cast(unsigned int, t01);
        o.y = __builtin_bit_cast(unsigned int, t23);
        o.z = __builtin_bit_cast(unsigned int, d01);
        o.w = __builtin_bit_cast(unsigned int, d23);
        *(uint4*)&Tp[e*4] = o;
    }
    // stage f16 f-chunk (128 rows x 64 f16)
    const unsigned short* fs = f16w + ((size_t)b*NB + jc*JCHUNK)*FD;
    for (int s = tid; s < JCHUNK*FD/4; s += 512)
        ((uint2*)f_l)[s] = ((const uint2*)fs)[s];
    // stage d tile (32 x 128 f32, padded stride)
    int i0 = it*ITILE;
    for (int s = tid; s < ITILE*JCHUNK/4; s += 512) {
        int r = s >> 5, c = s & 31;
        *(float4*)&d_l[r*DPAD + c*4] =
            *(const float4*)&dists[((size_t)b*NB + i0 + r)*NB + jc*JCHUNK + c*4];
    }
    __syncthreads();
    int wave = tid >> 6, lane = tid & 63;
    int g = lane >> 4, fq = lane & 15;
    int il = wave*4 + g;                 // 8 waves x 4 = 32 i's
    const float scale = 447.0f/5.0f;
    float a0 = 0.f, a1 = 0.f, a2 = 0.f, a3 = 0.f;
    const float* drow = &d_l[il*DPAD];
    const unsigned int* Tbase = Tp + fq*4;
    const unsigned int* fbase = f_l + fq*2;
    #pragma unroll 4
    for (int j = 0; j < JCHUNK; ++j) {
        float dv = drow[j];                       // b32, 16-way broadcast
        float tt = fminf(dv*scale, 446.999f);
        int k = (int)tt;
        float fr = tt - (float)k;
        uint4 tp = *(const uint4*)&Tbase[k*64];   // b128: T(4 f16) | dT(4 f16)
        uint2 fv = *(const uint2*)&fbase[j*32];   // b64: f_j (4 f16)
        _Float16 ah = (_Float16)fr;
        half2v av = { ah, ah };
        half2v W01 = __builtin_bit_cast(half2v, tp.z)*av + __builtin_bit_cast(half2v, tp.x);
        half2v W23 = __builtin_bit_cast(half2v, tp.w)*av + __builtin_bit_cast(half2v, tp.y);
        half2v f01 = __builtin_bit_cast(half2v, fv.x);
        half2v f23 = __builtin_bit_cast(half2v, fv.y);
        a0 += (float)W01[0] * (float)f01[0];
        a1 += (float)W01[1] * (float)f01[1];
        a2 += (float)W23[0] * (float)f23[0];
        a3 += (float)W23[1] * (float)f23[1];
    }
    float4 acc; acc.x = a0; acc.y = a1; acc.z = a2; acc.w = a3;
    *(float4*)&y_ws[((size_t)jc*2048 + (size_t)b*NB + i0 + il)*FD + fq*4] = acc;
}

// k_final: last post-MLP + residual + readout MLP
__global__ __launch_bounds__(256) void schnet_final(
    const float* __restrict__ x_in,
    const float* __restrict__ y_ws,
    const float* __restrict__ f2o, const float* __restrict__ f2b,
    const float* __restrict__ dw,  const float* __restrict__ db,
    const float* __restrict__ aw1, const float* __restrict__ ab1,
    const float* __restrict__ aw2, const float* __restrict__ ab2,
    float* __restrict__ out)
{
    __shared__ float wA[FD*FD], wB[FD*FD];
    __shared__ float wA1[FD*32];
    __shared__ float bA[FD], bB[FD], b1s[32], w2s[32];
    __shared__ float r1[4][FD], r2[4][FD];
    int tid = threadIdx.x, wg = blockIdx.x;
    for (int s = tid; s < FD*FD; s += 256) { wA[s] = f2o[2*FD*FD + s]; wB[s] = dw[2*FD*FD + s]; }
    for (int s = tid; s < FD*32; s += 256) wA1[s] = aw1[s];
    if (tid < FD) { bA[tid] = f2b[2*FD + tid]; bB[tid] = db[2*FD + tid]; }
    if (tid < 32) { b1s[tid] = ab1[tid]; w2s[tid] = aw2[tid]; }
    __syncthreads();
    int wave = tid >> 6, lane = tid & 63;
    float ab2v = ab2[0];
    for (int rr = 0; rr < 4; ++rr) {
        int row = wg*16 + wave*4 + rr;
        float y = 0.0f;
        for (int c = 0; c < 4; ++c) y += y_ws[((size_t)c*2048 + row)*FD + lane];
        r1[wave][lane] = y;
        __syncthreads();
        float z = bA[lane];
        for (int f = 0; f < FD; ++f) z += r1[wave][f] * wA[f*FD + lane];
        float u = ssp(z);
        r2[wave][lane] = u;
        __syncthreads();
        float y3 = bB[lane];
        for (int gg = 0; gg < FD; ++gg) y3 += r2[wave][gg] * wB[gg*FD + lane];
        float x3 = x_in[(size_t)row*FD + lane] + y3;
        r1[wave][lane] = x3;
        float s1 = b1s[lane & 31];
        for (int f = 0; f < FD; ++f) s1 += r1[wave][f] * wA1[f*32 + (lane & 31)];
        float hh = ssp(s1) * w2s[lane & 31];
        r2[wave][lane] = hh;
        __syncthreads();
        if (lane == 0) {
            float sum = ab2v;
            for (int m = 0; m < 32; ++m) sum += r2[wave][m];
            out[row] = sum;
        }
        __syncthreads();
    }
}

extern "C" void kernel_launch(void* const* d_in, const int* in_sizes, int n_in,
                              void* d_out, int out_size, void* d_ws, size_t ws_size,
                              hipStream_t stream) {
    const float* emb  = (const float*)d_in[0];
    const float* dist = (const float*)d_in[1];
    const float* in2f = (const float*)d_in[2];
    const float* fw1  = (const float*)d_in[3];
    const float* fb1  = (const float*)d_in[4];
    const float* fw2  = (const float*)d_in[5];
    const float* fb2  = (const float*)d_in[6];
    const float* f2o  = (const float*)d_in[7];
    const float* f2b  = (const float*)d_in[8];
    const float* dwp  = (const float*)d_in[9];
    const float* dbp  = (const float*)d_in[10];
    const float* aw1  = (const float*)d_in[11];
    const float* ab1  = (const float*)d_in[12];
    const float* aw2  = (const float*)d_in[13];
    const float* ab2  = (const float*)d_in[14];
    float* out = (float*)d_out;
    float* ws = (float*)d_ws;
    float* T_ws = ws;                                  // 448*64 = 28672 floats
    unsigned short* f16w = (unsigned short*)(ws + 28672); // 2048*64 f16 (65536 float slots)
    float* x_buf = ws + 28672 + 65536;                 // 131072 floats
    float* y_ws  = x_buf + 131072;                     // 4*2048*64 = 524288 floats
    for (int t = 0; t < 3; ++t) {
        hipLaunchKernelGGL(schnet_pre, dim3(240), dim3(256), 0, stream,
            t, emb, x_buf, y_ws, in2f, fw1, fb1, fw2, fb2, f2o, f2b, dwp, dbp, f16w, T_ws);
        hipLaunchKernelGGL(schnet_conv, dim3(256), dim3(512), 0, stream,
            dist, f16w, T_ws, y_ws);
    }
    hipLaunchKernelGGL(schnet_final, dim3(128), dim3(256), 0, stream,
        x_buf, y_ws, f2o, f2b, dwp, dbp, aw1, ab1, aw2, ab2, out);
}